// Round 4
// baseline (384.861 us; speedup 1.0000x reference)
//
#include <hip/hip_runtime.h>
#include <hip/hip_bf16.h>
#include <stdint.h>

#define BB 4
#define NN 4096
#define DD 128
#define BI 64   // i-rows per agg block
#define BJ 64   // j (K) per staged tile

typedef _Float16 f16;
typedef __attribute__((ext_vector_type(8))) _Float16 f16x8;
typedef __attribute__((ext_vector_type(4))) float f32x4;

typedef __attribute__((address_space(3))) uint32_t lds_u32_t;
typedef const __attribute__((address_space(1))) uint32_t glb_u32_t;

__device__ __forceinline__ void gload_lds16(const void* g, void* l) {
    __builtin_amdgcn_global_load_lds((glb_u32_t*)g, (lds_u32_t*)l, 16, 0, 0);
}

// ---------------- prep: x[b][j][d] -> xt fp16 [b][d][j] ----------------
__global__ void prep_xt(const float* __restrict__ x, f16* __restrict__ xt) {
    __shared__ float tile[32][33];
    int bid = blockIdx.x;
    int b = bid >> 9;              // 512 tiles per batch (128 j-tiles x 4 d-tiles)
    int rest = bid & 511;
    int j0 = (rest >> 2) * 32;
    int d0 = (rest & 3) * 32;
    int t = threadIdx.x;
#pragma unroll
    for (int p = 0; p < 4; ++p) {
        int idx = p * 256 + t;
        int jj = idx >> 5, dd = idx & 31;
        tile[jj][dd] = x[((size_t)b * NN + j0 + jj) * DD + d0 + dd];
    }
    __syncthreads();
#pragma unroll
    for (int p = 0; p < 4; ++p) {
        int idx = p * 256 + t;
        int dd = idx >> 5, jj = idx & 31;
        xt[((size_t)b * DD + d0 + dd) * NN + j0 + jj] = (f16)tile[jj][dd];
    }
}

// ---------------- prep: U[d][e] -> ut fp16 [e][d] ----------------
__global__ void prep_ut(const float* __restrict__ U, f16* __restrict__ ut) {
    __shared__ float tile[32][33];
    int bid = blockIdx.x;
    int d0 = (bid >> 2) * 32, e0 = (bid & 3) * 32;
    int t = threadIdx.x;
#pragma unroll
    for (int p = 0; p < 4; ++p) {
        int idx = p * 256 + t;
        int dd = idx >> 5, ee = idx & 31;
        tile[dd][ee] = U[(size_t)(d0 + dd) * DD + e0 + ee];
    }
    __syncthreads();
#pragma unroll
    for (int p = 0; p < 4; ++p) {
        int idx = p * 256 + t;
        int ee = idx >> 5, dd = idx & 31;
        ut[(size_t)(e0 + ee) * DD + d0 + dd] = (f16)tile[dd][ee];
    }
}

// ---------------- main: agg[b,i,d] = sum_j mask(adj[b,j,i]) * x[b,j,d]; deg ----------------
// 256 blocks (b, i0), 512 threads (8 waves). Tile: 64 i x 128 d, K-step 64 j.
// LDS rows are 64 f16 = 8 x 16B units; unit swizzle: u_lds = u_glb ^ ((row>>1)&7).
__global__ __launch_bounds__(512, 2) void agg_kernel(
    const float* __restrict__ adj, const f16* __restrict__ xt,
    float* __restrict__ agg, float* __restrict__ deg)
{
    __shared__ __align__(16) f16 mlds[2][BI * BJ];   // mask tile [i][j], 8KB each
    __shared__ __align__(16) f16 xlds[2][DD * BJ];   // xT tile [d][j], 16KB each
    __shared__ float degl[8][BI];

    const int t = threadIdx.x;
    const int w = t >> 6;    // wave 0..7
    const int l = t & 63;
    const int bid = blockIdx.x;
    const int b = bid >> 6;
    const int i0 = (bid & 63) * BI;

    const float* adjb = adj + (size_t)b * NN * NN + i0;
    const f16* xtb = xt + (size_t)b * DD * NN;

    const int si = l;        // i-row this thread stages
    const int su = w;        // 16B unit (8 j) this thread stages
    const int mwoff = (si * 8 + (su ^ ((si >> 1) & 7))) * 8;

    const int ifr = (w & 3) * 16;      // wave's i-fragment base
    const int dbase = (w >> 2) * 64;   // wave's d-half base

    f32x4 acc[4] = {f32x4{0,0,0,0}, f32x4{0,0,0,0}, f32x4{0,0,0,0}, f32x4{0,0,0,0}};
    float degp = 0.f;

    auto stage = [&](int jt, int buf) {
        const int j0 = jt * BJ;
        // xT tile via async global->LDS (linear LDS dest, pre-swizzled source)
#pragma unroll
        for (int c = 0; c < 2; ++c) {
            int g = (w * 2 + c) * 64 + l;       // linear 16B-unit index in tile
            int d = g >> 3, ul = g & 7;
            int ug = ul ^ ((d >> 1) & 7);
            gload_lds16(xtb + (size_t)d * NN + j0 + ug * 8, &xlds[buf][(size_t)g * 8]);
        }
        // adj tile: coalesced f32 loads (lane = i), convert->fp16 mask, transpose-write
        const float* src = adjb + (size_t)(j0 + su * 8) * NN + si;
        float v[8];
#pragma unroll
        for (int q = 0; q < 8; ++q) v[q] = src[(size_t)q * NN];
        f16x8 m8;
#pragma unroll
        for (int q = 0; q < 8; ++q) {
            degp += v[q];
            m8[q] = v[q] > 0.f ? (f16)1.f : (f16)0.f;
        }
        *(f16x8*)&mlds[buf][mwoff] = m8;
    };

    auto compute = [&](int buf) {
#pragma unroll
        for (int kk = 0; kk < 2; ++kk) {
            const int row = ifr + (l & 15);
            const int ug = kk * 4 + (l >> 4);
            f16x8 a = *(const f16x8*)&mlds[buf][(row * 8 + (ug ^ ((row >> 1) & 7))) * 8];
#pragma unroll
            for (int f = 0; f < 4; ++f) {
                const int d = dbase + f * 16 + (l & 15);
                f16x8 bb = *(const f16x8*)&xlds[buf][(d * 8 + (ug ^ ((d >> 1) & 7))) * 8];
                acc[f] = __builtin_amdgcn_mfma_f32_16x16x32_f16(a, bb, acc[f], 0, 0, 0);
            }
        }
    };

    stage(0, 0);
    for (int jt = 0; jt < NN / BJ; ++jt) {
        const int cur = jt & 1;
        __syncthreads();                      // staged tile `cur` ready
        if (jt + 1 < NN / BJ) stage(jt + 1, cur ^ 1);  // prefetch overlaps compute
        compute(cur);
    }

    // deg reduce: 8 partials per i
    degl[w][l] = degp;
    __syncthreads();
    if (t < BI) {
        float s = 0.f;
#pragma unroll
        for (int q = 0; q < 8; ++q) s += degl[q][t];
        deg[b * NN + i0 + t] = s;
    }

    // write agg f32 (C layout: col=lane&15, row=(lane>>4)*4+r)
    float* aggb = agg + ((size_t)b * NN + i0) * DD;
#pragma unroll
    for (int f = 0; f < 4; ++f) {
#pragma unroll
        for (int r = 0; r < 4; ++r) {
            int row = ifr + (l >> 4) * 4 + r;
            int col = dbase + f * 16 + (l & 15);
            aggb[(size_t)row * DD + col] = acc[f][r];
        }
    }
}

// ---------------- out = relu((agg @ U) / deg) ----------------
// 256 blocks x 64 rows, 256 threads (4 waves). Row = flat b*N+i.
__global__ __launch_bounds__(256, 2) void out_kernel(
    const float* __restrict__ agg, const f16* __restrict__ ut,
    const float* __restrict__ deg, float* __restrict__ out)
{
    __shared__ __align__(16) f16 alds[64 * DD];    // 16KB: [row][d], 16 units/row
    __shared__ __align__(16) f16 ulds[DD * DD];    // 32KB: [e][d], 16 units/row

    const int t = threadIdx.x;
    const int w = t >> 6, l = t & 63;
    const int row0 = blockIdx.x * 64;

    // stage uT via DMA (unit swizzle u ^ (row&7); 16 units/row)
#pragma unroll
    for (int c = 0; c < 8; ++c) {
        int g = (w * 8 + c) * 64 + l;
        int e = g >> 4, ul = g & 15;
        int ug = ul ^ (e & 7);
        gload_lds16(ut + (size_t)e * DD + ug * 8, &ulds[(size_t)g * 8]);
    }
    // stage agg rows: coalesced f32 loads, convert fp16, swizzled write
#pragma unroll
    for (int p = 0; p < 4; ++p) {
        int chunk = p * 256 + t;
        int row = chunk >> 4, ug = chunk & 15;
        const float* src = agg + (size_t)(row0 + row) * DD + ug * 8;
        f16x8 tmp;
#pragma unroll
        for (int q = 0; q < 8; ++q) tmp[q] = (f16)src[q];
        *(f16x8*)&alds[(row * 16 + (ug ^ (row & 7))) * 8] = tmp;
    }
    __syncthreads();

    f32x4 acc[8] = {f32x4{0,0,0,0}, f32x4{0,0,0,0}, f32x4{0,0,0,0}, f32x4{0,0,0,0},
                    f32x4{0,0,0,0}, f32x4{0,0,0,0}, f32x4{0,0,0,0}, f32x4{0,0,0,0}};
#pragma unroll
    for (int kk = 0; kk < 4; ++kk) {
        const int row = w * 16 + (l & 15);
        const int ug = kk * 4 + (l >> 4);
        f16x8 a = *(const f16x8*)&alds[(row * 16 + (ug ^ (row & 7))) * 8];
#pragma unroll
        for (int ef = 0; ef < 8; ++ef) {
            const int e = ef * 16 + (l & 15);
            f16x8 bb = *(const f16x8*)&ulds[(e * 16 + (ug ^ (e & 7))) * 8];
            acc[ef] = __builtin_amdgcn_mfma_f32_16x16x32_f16(a, bb, acc[ef], 0, 0, 0);
        }
    }

    float rdeg[4];
#pragma unroll
    for (int r = 0; r < 4; ++r)
        rdeg[r] = 1.0f / deg[row0 + w * 16 + (l >> 4) * 4 + r];

    float* outb = out + (size_t)(row0 + w * 16) * DD;
#pragma unroll
    for (int ef = 0; ef < 8; ++ef) {
#pragma unroll
        for (int r = 0; r < 4; ++r) {
            float vv = acc[ef][r] * rdeg[r];
            outb[(size_t)((l >> 4) * 4 + r) * DD + ef * 16 + (l & 15)] = vv > 0.f ? vv : 0.f;
        }
    }
}

extern "C" void kernel_launch(void* const* d_in, const int* in_sizes, int n_in,
                              void* d_out, int out_size, void* d_ws, size_t ws_size,
                              hipStream_t stream) {
    const float* x   = (const float*)d_in[0];
    const float* adj = (const float*)d_in[1];
    const float* U   = (const float*)d_in[2];
    float* out = (float*)d_out;

    char* ws = (char*)d_ws;
    f16* xt  = (f16*)ws;                                              // 4 MB
    f16* ut  = (f16*)(ws + (size_t)BB * DD * NN * 2);                 // 32 KB
    float* agg = (float*)(ws + (size_t)BB * DD * NN * 2 + DD * DD * 2);  // 8.4 MB
    float* deg = (float*)((char*)agg + (size_t)BB * NN * DD * 4);     // 64 KB

    hipLaunchKernelGGL(prep_xt, dim3(BB * (NN / 32) * (DD / 32)), dim3(256), 0, stream, x, xt);
    hipLaunchKernelGGL(prep_ut, dim3((DD / 32) * (DD / 32)), dim3(256), 0, stream, U, ut);
    hipLaunchKernelGGL(agg_kernel, dim3(BB * (NN / BI)), dim3(512), 0, stream, adj, xt, agg, deg);
    hipLaunchKernelGGL(out_kernel, dim3((BB * NN) / 64), dim3(256), 0, stream, agg, ut, deg, out);
}

// Round 9
// 382.980 us; speedup vs baseline: 1.0049x; 1.0049x over previous
//
#include <hip/hip_runtime.h>
#include <hip/hip_bf16.h>
#include <stdint.h>

#define BB 4
#define NN 4096
#define DD 128
#define BI 64   // i-rows per block
#define BJ 64   // j (K) per staged tile
#define NT (NN / BJ)

typedef _Float16 f16;
typedef __attribute__((ext_vector_type(8))) _Float16 f16x8;
typedef __attribute__((ext_vector_type(4))) float f32x4;

typedef __attribute__((address_space(3))) uint32_t lds_u32_t;
typedef const __attribute__((address_space(1))) uint32_t glb_u32_t;

__device__ __forceinline__ void gload_lds16(const void* g, void* l) {
    __builtin_amdgcn_global_load_lds((glb_u32_t*)g, (lds_u32_t*)l, 16, 0, 0);
}

// ---------------- prep: x[b][j][d] -> xt fp16 [b][d][j] ----------------
__global__ void prep_xt(const float* __restrict__ x, f16* __restrict__ xt) {
    __shared__ float tile[32][33];
    int bid = blockIdx.x;
    int b = bid >> 9;
    int rest = bid & 511;
    int j0 = (rest >> 2) * 32;
    int d0 = (rest & 3) * 32;
    int t = threadIdx.x;
#pragma unroll
    for (int p = 0; p < 4; ++p) {
        int idx = p * 256 + t;
        int jj = idx >> 5, dd = idx & 31;
        tile[jj][dd] = x[((size_t)b * NN + j0 + jj) * DD + d0 + dd];
    }
    __syncthreads();
#pragma unroll
    for (int p = 0; p < 4; ++p) {
        int idx = p * 256 + t;
        int dd = idx >> 5, jj = idx & 31;
        xt[((size_t)b * DD + d0 + dd) * NN + j0 + jj] = (f16)tile[jj][dd];
    }
}

// ---------------- prep: U[d][e] -> ut fp16 [e][d] ----------------
__global__ void prep_ut(const float* __restrict__ U, f16* __restrict__ ut) {
    __shared__ float tile[32][33];
    int bid = blockIdx.x;
    int d0 = (bid >> 2) * 32, e0 = (bid & 3) * 32;
    int t = threadIdx.x;
#pragma unroll
    for (int p = 0; p < 4; ++p) {
        int idx = p * 256 + t;
        int dd = idx >> 5, ee = idx & 31;
        tile[dd][ee] = U[(size_t)(d0 + dd) * DD + e0 + ee];
    }
    __syncthreads();
#pragma unroll
    for (int p = 0; p < 4; ++p) {
        int idx = p * 256 + t;
        int ee = idx >> 5, dd = idx & 31;
        ut[(size_t)(e0 + ee) * DD + d0 + dd] = (f16)tile[dd][ee];
    }
}

// ---------------- fused: agg (masked adj^T @ x) + deg + (agg@U)/deg + relu ----------------
// 256 blocks (b, i0), 512 threads (8 waves). Tile 64 i x 128 d, K-step 64 j.
// K-loop: T14 split — issue adj loads(jt+1) / DMA xt(jt+1), compute(jt), then
// convert+ds_write(jt+1) (vmcnt wait lands AFTER compute, hiding HBM latency).
// Epilogue reuses loop LDS: alds (<-mlds, 16KB) agg f16; ulds (<-xlds, 32KB) U^T.
__global__ __launch_bounds__(512, 2) void fused_kernel(
    const float* __restrict__ adj, const f16* __restrict__ xt,
    const f16* __restrict__ ut, float* __restrict__ out)
{
    __shared__ __align__(16) f16 mlds[2][BI * BJ];   // mask [i][j], 8KB each
    __shared__ __align__(16) f16 xlds[2][DD * BJ];   // xT [d][j], 16KB each
    __shared__ float degl[8][BI];
    __shared__ float degs[BI];

    const int t = threadIdx.x;
    const int w = t >> 6;
    const int l = t & 63;
    const int bid = blockIdx.x;
    const int b = bid >> 6;
    const int i0 = (bid & 63) * BI;

    const float* adjb = adj + (size_t)b * NN * NN + i0;
    const f16* xtb = xt + (size_t)b * DD * NN;

    const int si = l;   // i-column this thread stages
    const int su = w;   // 8-row j-group this thread stages
    const int mwoff = (si * 8 + (su ^ ((si >> 1) & 7))) * 8;

    const int ifr = (w & 3) * 16;      // wave's i-fragment base
    const int dbase = (w >> 2) * 64;   // wave's d-half base

    f32x4 acc[4] = {f32x4{0,0,0,0}, f32x4{0,0,0,0}, f32x4{0,0,0,0}, f32x4{0,0,0,0}};
    float degp = 0.f;
    float v[8];

    auto load_adj = [&](int jt) {
        const float* src = adjb + (size_t)(jt * BJ + su * 8) * NN + si;
#pragma unroll
        for (int q = 0; q < 8; ++q) v[q] = src[(size_t)q * NN];
    };
    auto dma_xt = [&](int jt, int buf) {
        const int j0 = jt * BJ;
#pragma unroll
        for (int c = 0; c < 2; ++c) {
            int g = (w * 2 + c) * 64 + l;     // linear 16B-unit index
            int d = g >> 3, ul = g & 7;
            int ug = ul ^ ((d >> 1) & 7);     // pre-swizzled source (rule #21)
            gload_lds16(xtb + (size_t)d * NN + j0 + ug * 8, &xlds[buf][(size_t)g * 8]);
        }
    };
    auto convert_write = [&](int buf) {
        f16x8 m8;
#pragma unroll
        for (int q = 0; q < 8; ++q) {
            degp += v[q];
            m8[q] = v[q] > 0.f ? (f16)1.f : (f16)0.f;
        }
        *(f16x8*)&mlds[buf][mwoff] = m8;
    };
    auto compute = [&](int buf) {
#pragma unroll
        for (int kk = 0; kk < 2; ++kk) {
            const int row = ifr + (l & 15);
            const int ug = kk * 4 + (l >> 4);
            f16x8 a = *(const f16x8*)&mlds[buf][(row * 8 + (ug ^ ((row >> 1) & 7))) * 8];
#pragma unroll
            for (int f = 0; f < 4; ++f) {
                const int d = dbase + f * 16 + (l & 15);
                f16x8 bb = *(const f16x8*)&xlds[buf][(d * 8 + (ug ^ ((d >> 1) & 7))) * 8];
                acc[f] = __builtin_amdgcn_mfma_f32_16x16x32_f16(a, bb, acc[f], 0, 0, 0);
            }
        }
    };

    // prologue: tile 0
    load_adj(0);
    dma_xt(0, 0);
    convert_write(0);
    __syncthreads();

    for (int jt = 0; jt < NT; ++jt) {
        const int cur = jt & 1;
        if (jt + 1 < NT) {
            load_adj(jt + 1);            // issue early (T14)
            dma_xt(jt + 1, cur ^ 1);
        }
        compute(cur);                    // independent of v — hides load latency
        if (jt + 1 < NT) convert_write(cur ^ 1);  // vmcnt wait lands here
        __syncthreads();
    }

    // ---- epilogue: out = relu((agg @ U) / deg) ----
    degl[w][l] = degp;
    __syncthreads();                     // all K-loop LDS reads done; buffers free

    f16* alds = &mlds[0][0];             // 16KB: agg f16 [row][16 units], swz u^(row&7)
    f16* ulds = &xlds[0][0];             // 32KB: U^T [e][16 units], swz u^(e&7)

    // stage U^T via DMA (2048 units, 4/thread), pre-swizzled source
#pragma unroll
    for (int c = 0; c < 4; ++c) {
        int g = (w * 4 + c) * 64 + l;
        int e = g >> 4, ul = g & 15;
        int ug = ul ^ (e & 7);
        gload_lds16(ut + (size_t)e * DD + ug * 8, &ulds[(size_t)g * 8]);
    }
    // acc -> alds (f16, swizzled scalar writes; one-time cost)
#pragma unroll
    for (int f = 0; f < 4; ++f) {
#pragma unroll
        for (int r = 0; r < 4; ++r) {
            int row = ifr + (l >> 4) * 4 + r;
            int col = dbase + f * 16 + (l & 15);
            alds[(row * 16 + ((col >> 3) ^ (row & 7))) * 8 + (col & 7)] = (f16)acc[f][r];
        }
    }
    if (t < BI) {
        float s = 0.f;
#pragma unroll
        for (int q = 0; q < 8; ++q) s += degl[q][t];
        degs[t] = s;
    }
    __syncthreads();                     // drains DMA + ds writes

    // wave w: rows (w&3)*16.., e-half (w>>2)*64
    const int ifr2 = (w & 3) * 16;
    const int ebase = (w >> 2) * 64;
    f32x4 acc2[4] = {f32x4{0,0,0,0}, f32x4{0,0,0,0}, f32x4{0,0,0,0}, f32x4{0,0,0,0}};
#pragma unroll
    for (int kk = 0; kk < 4; ++kk) {
        const int row = ifr2 + (l & 15);
        const int ug = kk * 4 + (l >> 4);
        f16x8 a = *(const f16x8*)&alds[(row * 16 + (ug ^ (row & 7))) * 8];
#pragma unroll
        for (int ef = 0; ef < 4; ++ef) {
            const int e = ebase + ef * 16 + (l & 15);
            f16x8 bb = *(const f16x8*)&ulds[(e * 16 + (ug ^ (e & 7))) * 8];
            acc2[ef] = __builtin_amdgcn_mfma_f32_16x16x32_f16(a, bb, acc2[ef], 0, 0, 0);
        }
    }

    float rdeg[4];
#pragma unroll
    for (int r = 0; r < 4; ++r)
        rdeg[r] = 1.0f / degs[ifr2 + (l >> 4) * 4 + r];

    float* outb = out + ((size_t)b * NN + i0) * DD;
#pragma unroll
    for (int ef = 0; ef < 4; ++ef) {
#pragma unroll
        for (int r = 0; r < 4; ++r) {
            int row = ifr2 + (l >> 4) * 4 + r;
            int e = ebase + ef * 16 + (l & 15);
            float vv = acc2[ef][r] * rdeg[r];
            outb[(size_t)row * DD + e] = vv > 0.f ? vv : 0.f;
        }
    }
}

extern "C" void kernel_launch(void* const* d_in, const int* in_sizes, int n_in,
                              void* d_out, int out_size, void* d_ws, size_t ws_size,
                              hipStream_t stream) {
    const float* x   = (const float*)d_in[0];
    const float* adj = (const float*)d_in[1];
    const float* U   = (const float*)d_in[2];
    float* out = (float*)d_out;

    char* ws = (char*)d_ws;
    f16* xt = (f16*)ws;                                   // 4 MB
    f16* ut = (f16*)(ws + (size_t)BB * DD * NN * 2);      // 32 KB

    hipLaunchKernelGGL(prep_xt, dim3(BB * (NN / 32) * (DD / 32)), dim3(256), 0, stream, x, xt);
    hipLaunchKernelGGL(prep_ut, dim3((DD / 32) * (DD / 32)), dim3(256), 0, stream, U, ut);
    hipLaunchKernelGGL(fused_kernel, dim3(BB * (NN / BI)), dim3(512), 0, stream, adj, xt, ut, out);
}